// Round 1
// baseline (378.202 us; speedup 1.0000x reference)
//
#include <hip/hip_runtime.h>

#define AW 264   // fp16 elems per activation LDS row (256 + 8 pad)
#define YW 136   // f32 elems per Ys row (128 + 8 pad)

typedef _Float16 f16x8 __attribute__((ext_vector_type(8)));
typedef _Float16 f16x4 __attribute__((ext_vector_type(4)));
typedef __attribute__((ext_vector_type(4))) float f32x4;
typedef __attribute__((ext_vector_type(2))) float f32x2;

// 5-op tanh: 1 - 2/(e^{2x}+1). Safe at +/-inf. |err| ~1e-7.
__device__ __forceinline__ float fast_tanh(float x) {
    float e = __expf(2.0f * x);
    return 1.0f - 2.0f / (e + 1.0f);
}
// Workgroup barrier ordering LDS only — does NOT drain vmcnt, so global
// loads issued before it stay in flight across it.
__device__ __forceinline__ void bar_lds() {
    asm volatile("s_waitcnt lgkmcnt(0)\n\ts_barrier" ::: "memory");
}

// ---------------- fused precompute: weights -> MFMA fragment layout, hi/lo fp16 ----
// F layout: [plane][nt][kc][lane(64)][j(8)]; value = W[n*K+k], n=nt*16+(l&15),
// k=kc*32+(l>>4)*8+j. Same lane formula serves as A- or B-operand fragment.
__global__ __launch_bounds__(256) void pk_all(
    const float* __restrict__ Wvf1, const float* __restrict__ Wvf2,
    const float* __restrict__ Wm,   const float* __restrict__ bm,
    const float* __restrict__ logsig,
    _Float16* __restrict__ W1F, _Float16* __restrict__ W2F,
    _Float16* __restrict__ A3F, float* __restrict__ c_all)
{
    __shared__ float ls[32][62];
    const int b = blockIdx.x, t = threadIdx.x;
    if (b < 128) {                      // W1: N=256 x K=128 (16 nt, 4 kc)
        int u = b * 256 + t;
        int j = u & 7, l = (u >> 3) & 63;
        int kc = (u >> 9) & 3, nt = (u >> 9) >> 2;
        int n = nt * 16 + (l & 15), k = kc * 32 + (l >> 4) * 8 + j;
        float w = Wvf1[n * 128 + k];
        _Float16 hi = (_Float16)w;
        W1F[u] = hi;
        W1F[32768 + u] = (_Float16)(w - (float)hi);
    } else if (b < 384) {               // W2: 256x256 (16 nt, 8 kc)
        int u = (b - 128) * 256 + t;
        int j = u & 7, l = (u >> 3) & 63;
        int kc = (u >> 9) & 7, nt = (u >> 9) >> 3;
        int n = nt * 16 + (l & 15), k = kc * 32 + (l >> 4) * 8 + j;
        float w = Wvf2[n * 256 + k];
        _Float16 hi = (_Float16)w;
        W2F[u] = hi;
        W2F[65536 + u] = (_Float16)(w - (float)hi);
    } else if (b < 512) {               // A_r: ALL 32 r per block -> Wm read once
        for (int e2 = t; e2 < 32 * 62; e2 += 256)
            ls[e2 / 62][e2 % 62] = logsig[(e2 / 62) * 63 + 1 + (e2 % 62)];
        __syncthreads();
        int u = (b - 384) * 256 + t;
        int j = u & 7, l = (u >> 3) & 63, kc = (u >> 9) & 7, nt = (u >> 12) & 7;
        int h = nt * 16 + (l & 15);
        int v = kc * 32 + (l >> 4) * 8 + j;
        float acc[32];
#pragma unroll
        for (int r = 0; r < 32; r++) acc[r] = 0.f;
        const float* wp = Wm + (h * 62) * 256 + v;
        for (int ll = 0; ll < 62; ll += 2) {       // 2 loads in flight per iter
            float w0 = wp[ll * 256];
            float w1 = wp[ll * 256 + 256];
#pragma unroll
            for (int r = 0; r < 32; r++) {
                f32x2 lv = *(const f32x2*)&ls[r][ll];   // 8B-aligned (248r+4ll)
                acc[r] += w0 * lv.x + w1 * lv.y;
            }
        }
#pragma unroll
        for (int r = 0; r < 32; r++) {
            _Float16 hi = (_Float16)acc[r];
            A3F[r * 65536 + u] = hi;
            A3F[r * 65536 + 32768 + u] = (_Float16)(acc[r] - (float)hi);
        }
    } else {                            // c_r[h] = bm[h,:] . seg_r
        int u = (b - 512) * 256 + t;
        int r = u >> 7, h = u & 127;
        float acc = 0.f;
        for (int ll = 0; ll < 62; ll++) acc += bm[h * 62 + ll] * logsig[r * 63 + 1 + ll];
        c_all[u] = acc;
    }
}

// ---------------- main fused kernel: 32 blocks x 16 rows, 8 waves, 20-step Heun ---
// v2: W1 hi/lo fragments WAVE-RESIDENT IN REGISTERS (64 VGPR, loaded once) —
// removes 128KB LDS + 16 LDS b128 reads/wave/eval. Activations PING-PONG
// between two hi/lo buffers: each stage reads P, writes Q, ONE barrier
// (3 bar/eval instead of 6). W2 + A_r windows stream from L2 as before.
// Transposed MFMA (weights = A-operand), fp16 hi/lo 3-chain (absmax 0.0039).
__global__ __launch_bounds__(512, 2) void rde_main(
    const float* __restrict__ ts, const float* __restrict__ x0,
    const float* __restrict__ intervals,
    const float* __restrict__ b1g, const float* __restrict__ b2g,
    const float* __restrict__ Win, const float* __restrict__ bin,
    const float* __restrict__ Wout, const float* __restrict__ bout,
    const _Float16* __restrict__ W1F, const _Float16* __restrict__ W2F,
    const _Float16* __restrict__ A3F, const float* __restrict__ c_all,
    float* __restrict__ out)
{
    // ABUF[0]=H buf0, [1]=L buf0, [2]=H buf1, [3]=L buf1  (ping-pong acts)
    __shared__ __align__(16) _Float16 ABUF[4][16 * AW];
    __shared__ float Ys[16 * YW];
    __shared__ float ivl[33];
    __shared__ int   r_arr[40];
    __shared__ float s_arr[40];
    __shared__ float lg[16][12];

    const int t    = threadIdx.x;
    const int lane = t & 63;
    const int wv   = t >> 6;        // wave 0..7
    const int m16  = lane & 15;     // batch row within tile
    const int q    = lane >> 4;
    const int row0 = blockIdx.x * 16;

    // W1 hi/lo fragments -> registers, once (coalesced: lane*16B contiguous)
    f16x8 w1h[2][4], w1l[2][4];
#pragma unroll
    for (int tt = 0; tt < 2; tt++)
#pragma unroll
        for (int kc = 0; kc < 4; kc++) {
            const _Float16* p = W1F + (((wv * 2 + tt) * 4 + kc) * 64 + lane) * 8;
            w1h[tt][kc] = *(const f16x8*)p;
            w1l[tt][kc] = *(const f16x8*)(p + 32768);
        }

    if (t < 33) ivl[t] = intervals[t];
    __syncthreads();

    const float ts0 = ts[0];
    const float dt  = __fdiv_rn(ts[32] - ts0, 20.0f);   // bit-exact vs reference

    if (t < 40) {   // searchsorted idx + 1/delta for all 40 VF evals
        int i = t >> 1;
        float tv = ts0 + (float)i * dt;
        if (t & 1) tv += dt;
        int p = 0;
        for (int j2 = 0; j2 < 32; j2++) p += (ivl[1 + j2] < tv) ? 1 : 0;
        int idx = p + 1;
        idx = idx < 1 ? 1 : idx;
        idx = idx > 32 ? 32 : idx;
        r_arr[t] = idx - 1;
        s_arr[t] = __fdiv_rn(1.0f, ivl[idx] - ivl[idx - 1]);
    }

    // biases along D rows (q*4+r) for this wave's stage1/2 n-tiles wv*2, wv*2+1
    f32x4 b1f[2], b2f[2];
#pragma unroll
    for (int tt = 0; tt < 2; tt++) {
        b1f[tt] = *(const f32x4*)(b1g + (wv * 2 + tt) * 16 + q * 4);
        b2f[tt] = *(const f32x4*)(b2g + (wv * 2 + tt) * 16 + q * 4);
    }

    // y0 = x0 @ Win.T + bin -> Y regs + buf0 (stage3 D layout: rows q*4+r, col wv*16+m16)
    float Y[4], K1[4];
    {
        const float* xr = x0 + (row0 + m16) * 5;
        float xv[5];
#pragma unroll
        for (int d = 0; d < 5; d++) xv[d] = xr[d];
        int h0 = wv * 16 + q * 4;
        f16x4 hv, lv;
#pragma unroll
        for (int r = 0; r < 4; r++) {
            float acc = bin[h0 + r];
#pragma unroll
            for (int d = 0; d < 5; d++) acc += xv[d] * Win[(h0 + r) * 5 + d];
            Y[r] = acc;
            K1[r] = 0.f;
            _Float16 hi = (_Float16)acc;
            hv[r] = hi;
            lv[r] = (_Float16)(acc - (float)hi);
        }
        *(f16x4*)(&ABUF[0][m16 * AW + h0]) = hv;    // 512 thr x 4 = full 16x128
        *(f16x4*)(&ABUF[1][m16 * AW + h0]) = lv;
    }
    __syncthreads();

    // One VF eval. pb/qb are compile-time after inlining -> static LDS indexing.
    // S1: read P(y) write Q(h1); bar; S2: read Q write P(h2); bar; S3: read P,
    // Heun-commit y' -> Q; bar. Writes always target a buffer whose readers
    // all passed the previous barrier.
    auto EVAL = [&](int e, int half, int pb, int qb) {
        const int ri   = r_arr[e];
        const float s  = s_arr[e];
        const _Float16* ABase = A3F + ri * 65536;

        // ---- stage1: h1 = relu(W1 . y), K=128; W1 frags in registers ----
        // issue W2 window A (kc 0..3) first — in flight across all of stage1
        f16x8 w2a[2][4][2];
#pragma unroll
        for (int tt = 0; tt < 2; tt++)
#pragma unroll
            for (int kc = 0; kc < 4; kc++) {
                const _Float16* bp = W2F + (((wv * 2 + tt) * 8 + kc) * 64 + lane) * 8;
                w2a[tt][kc][0] = *(const f16x8*)bp;
                w2a[tt][kc][1] = *(const f16x8*)(bp + 65536);
            }
        f32x4 aA[2], aB[2], aC[2];
#pragma unroll
        for (int tt = 0; tt < 2; tt++) {
            aA[tt] = b1f[tt];
            aB[tt] = (f32x4){0.f, 0.f, 0.f, 0.f};
            aC[tt] = (f32x4){0.f, 0.f, 0.f, 0.f};
        }
#pragma unroll
        for (int kc = 0; kc < 4; kc++) {
            int ao = m16 * AW + kc * 32 + q * 8;
            f16x8 ah = *(const f16x8*)(&ABUF[pb][ao]);
            f16x8 al = *(const f16x8*)(&ABUF[pb + 1][ao]);
#pragma unroll
            for (int tt = 0; tt < 2; tt++) {
                aA[tt] = __builtin_amdgcn_mfma_f32_16x16x32_f16(w1h[tt][kc], ah, aA[tt], 0, 0, 0);
                aB[tt] = __builtin_amdgcn_mfma_f32_16x16x32_f16(w1l[tt][kc], ah, aB[tt], 0, 0, 0);
                aC[tt] = __builtin_amdgcn_mfma_f32_16x16x32_f16(w1h[tt][kc], al, aC[tt], 0, 0, 0);
            }
        }
#pragma unroll
        for (int tt = 0; tt < 2; tt++) {        // commit h1 -> Q, packed b64
            int n0 = (wv * 2 + tt) * 16 + q * 4;
            f16x4 hv, lv;
#pragma unroll
            for (int r = 0; r < 4; r++) {       // D: col=lane&15 (m), row=q*4+r (n)
                float v = fmaxf(aA[tt][r] + aB[tt][r] + aC[tt][r], 0.f);
                _Float16 hi = (_Float16)v;
                hv[r] = hi;
                lv[r] = (_Float16)(v - (float)hi);
            }
            *(f16x4*)(&ABUF[qb][m16 * AW + n0]) = hv;
            *(f16x4*)(&ABUF[qb + 1][m16 * AW + n0]) = lv;
        }
        bar_lds();

        // ---- stage2: h2 = tanh(W2 . h1), K=256; w2a preloaded, w2b issued now ----
        f16x8 w2b[2][4][2];
#pragma unroll
        for (int tt = 0; tt < 2; tt++)
#pragma unroll
            for (int kc = 0; kc < 4; kc++) {
                const _Float16* bp = W2F + (((wv * 2 + tt) * 8 + 4 + kc) * 64 + lane) * 8;
                w2b[tt][kc][0] = *(const f16x8*)bp;
                w2b[tt][kc][1] = *(const f16x8*)(bp + 65536);
            }
#pragma unroll
        for (int tt = 0; tt < 2; tt++) {
            aA[tt] = b2f[tt];
            aB[tt] = (f32x4){0.f, 0.f, 0.f, 0.f};
            aC[tt] = (f32x4){0.f, 0.f, 0.f, 0.f};
        }
#pragma unroll
        for (int kc = 0; kc < 4; kc++) {        // first half with w2a
            int ao = m16 * AW + kc * 32 + q * 8;
            f16x8 ah = *(const f16x8*)(&ABUF[qb][ao]);
            f16x8 al = *(const f16x8*)(&ABUF[qb + 1][ao]);
#pragma unroll
            for (int tt = 0; tt < 2; tt++) {
                aA[tt] = __builtin_amdgcn_mfma_f32_16x16x32_f16(w2a[tt][kc][0], ah, aA[tt], 0, 0, 0);
                aB[tt] = __builtin_amdgcn_mfma_f32_16x16x32_f16(w2a[tt][kc][1], ah, aB[tt], 0, 0, 0);
                aC[tt] = __builtin_amdgcn_mfma_f32_16x16x32_f16(w2a[tt][kc][0], al, aC[tt], 0, 0, 0);
            }
        }
        // issue A_r window A (kc 0..3; stage3 n-tile = wv) + c vector
        f16x8 a3a[4][2];
#pragma unroll
        for (int kc = 0; kc < 4; kc++) {
            const _Float16* bp = ABase + ((wv * 8 + kc) * 64 + lane) * 8;
            a3a[kc][0] = *(const f16x8*)bp;
            a3a[kc][1] = *(const f16x8*)(bp + 32768);
        }
        f32x4 cf = *(const f32x4*)(c_all + ri * 128 + wv * 16 + q * 4);
#pragma unroll
        for (int kc = 0; kc < 4; kc++) {        // second half with w2b
            int ao = m16 * AW + (4 + kc) * 32 + q * 8;
            f16x8 ah = *(const f16x8*)(&ABUF[qb][ao]);
            f16x8 al = *(const f16x8*)(&ABUF[qb + 1][ao]);
#pragma unroll
            for (int tt = 0; tt < 2; tt++) {
                aA[tt] = __builtin_amdgcn_mfma_f32_16x16x32_f16(w2b[tt][kc][0], ah, aA[tt], 0, 0, 0);
                aB[tt] = __builtin_amdgcn_mfma_f32_16x16x32_f16(w2b[tt][kc][1], ah, aB[tt], 0, 0, 0);
                aC[tt] = __builtin_amdgcn_mfma_f32_16x16x32_f16(w2b[tt][kc][0], al, aC[tt], 0, 0, 0);
            }
        }
        // issue A_r window B (kc 4..7)
        f16x8 a3b[4][2];
#pragma unroll
        for (int kc = 0; kc < 4; kc++) {
            const _Float16* bp = ABase + ((wv * 8 + 4 + kc) * 64 + lane) * 8;
            a3b[kc][0] = *(const f16x8*)bp;
            a3b[kc][1] = *(const f16x8*)(bp + 32768);
        }
#pragma unroll
        for (int tt = 0; tt < 2; tt++) {        // commit h2 (tanh) -> P
            int n0 = (wv * 2 + tt) * 16 + q * 4;
            f16x4 hv, lv;
#pragma unroll
            for (int r = 0; r < 4; r++) {
                float v = fast_tanh(aA[tt][r] + aB[tt][r] + aC[tt][r]);
                _Float16 hi = (_Float16)v;
                hv[r] = hi;
                lv[r] = (_Float16)(v - (float)hi);
            }
            *(f16x4*)(&ABUF[pb][m16 * AW + n0]) = hv;
            *(f16x4*)(&ABUF[pb + 1][m16 * AW + n0]) = lv;
        }
        bar_lds();

        // ---- stage3: k = (A_r . h2 + c) * s ----
        f32x4 kA = cf;
        f32x4 kB = (f32x4){0.f, 0.f, 0.f, 0.f};
        f32x4 kC = (f32x4){0.f, 0.f, 0.f, 0.f};
#pragma unroll
        for (int kc = 0; kc < 4; kc++) {        // kc 0..3 with a3a
            int ao = m16 * AW + kc * 32 + q * 8;
            f16x8 ah = *(const f16x8*)(&ABUF[pb][ao]);
            f16x8 al = *(const f16x8*)(&ABUF[pb + 1][ao]);
            kA = __builtin_amdgcn_mfma_f32_16x16x32_f16(a3a[kc][0], ah, kA, 0, 0, 0);
            kB = __builtin_amdgcn_mfma_f32_16x16x32_f16(a3a[kc][1], ah, kB, 0, 0, 0);
            kC = __builtin_amdgcn_mfma_f32_16x16x32_f16(a3a[kc][0], al, kC, 0, 0, 0);
        }
#pragma unroll
        for (int kc = 0; kc < 4; kc++) {        // kc 4..7 with a3b
            int ao = m16 * AW + (4 + kc) * 32 + q * 8;
            f16x8 ah = *(const f16x8*)(&ABUF[pb][ao]);
            f16x8 al = *(const f16x8*)(&ABUF[pb + 1][ao]);
            kA = __builtin_amdgcn_mfma_f32_16x16x32_f16(a3b[kc][0], ah, kA, 0, 0, 0);
            kB = __builtin_amdgcn_mfma_f32_16x16x32_f16(a3b[kc][1], ah, kB, 0, 0, 0);
            kC = __builtin_amdgcn_mfma_f32_16x16x32_f16(a3b[kc][0], al, kC, 0, 0, 0);
        }
        {                                       // Heun commit + y' -> Q
            int h0 = wv * 16 + q * 4;
            f16x4 hv, lv;
#pragma unroll
            for (int r = 0; r < 4; r++) {
                float kv = (kA[r] + kB[r] + kC[r]) * s;
                float yn;
                if (half == 0) {                 // k1: stash, form y+dt*k1
                    K1[r] = kv;
                    yn = Y[r] + dt * kv;
                } else {                         // k2: y += 0.5*dt*(k1+k2)
                    yn = Y[r] + 0.5f * dt * (K1[r] + kv);
                    Y[r] = yn;
                }
                _Float16 hi = (_Float16)yn;
                hv[r] = hi;
                lv[r] = (_Float16)(yn - (float)hi);
            }
            *(f16x4*)(&ABUF[qb][m16 * AW + h0]) = hv;
            *(f16x4*)(&ABUF[qb + 1][m16 * AW + h0]) = lv;
        }
        bar_lds();
    };

#pragma unroll 1
    for (int e2 = 0; e2 < 20; e2++) {
        EVAL(2 * e2,     0, 0, 2);   // y in buf0 -> y' in buf1
        EVAL(2 * e2 + 1, 1, 2, 0);   // y in buf1 -> y' in buf0
    }

    // epilogue: Y regs -> Ys f32 [m][h]
#pragma unroll
    for (int r = 0; r < 4; r++)
        Ys[m16 * YW + wv * 16 + q * 4 + r] = Y[r];
    __syncthreads();
    if (t < 160) {                  // logits
        int m = t / 10, c = t % 10;
        float acc = bout[c];
        for (int k = 0; k < 128; k++) acc += Ys[m * YW + k] * Wout[c * 128 + k];
        lg[m][c] = acc;
    }
    __syncthreads();
    if (t < 16) {                   // softmax
        float mx = -1e30f;
#pragma unroll
        for (int c = 0; c < 10; c++) mx = fmaxf(mx, lg[t][c]);
        float ex[10], sum = 0.f;
#pragma unroll
        for (int c = 0; c < 10; c++) { ex[c] = expf(lg[t][c] - mx); sum += ex[c]; }
        float inv = __fdiv_rn(1.0f, sum);
#pragma unroll
        for (int c = 0; c < 10; c++) out[(row0 + t) * 10 + c] = ex[c] * inv;
    }
}

extern "C" void kernel_launch(void* const* d_in, const int* in_sizes, int n_in,
                              void* d_out, int out_size, void* d_ws, size_t ws_size,
                              hipStream_t stream) {
    const float* ts     = (const float*)d_in[0];
    const float* logsig = (const float*)d_in[1];
    const float* x0     = (const float*)d_in[2];
    const float* ivls   = (const float*)d_in[3];
    const float* Wvf1   = (const float*)d_in[4];
    const float* bvf1   = (const float*)d_in[5];
    const float* Wvf2   = (const float*)d_in[6];
    const float* bvf2   = (const float*)d_in[7];
    const float* Wm     = (const float*)d_in[8];
    const float* bm     = (const float*)d_in[9];
    const float* Win    = (const float*)d_in[10];
    const float* bin    = (const float*)d_in[11];
    const float* Wout   = (const float*)d_in[12];
    const float* bout   = (const float*)d_in[13];

    _Float16* W1F = (_Float16*)d_ws;            // 65536 halfs (128KB, hi+lo)
    _Float16* W2F = W1F + 65536;                // 131072 halfs (256KB, hi+lo)
    _Float16* A3F = W2F + 131072;               // 32*65536 halfs (4MB, hi+lo per r)
    float* c_all = (float*)(A3F + 32 * 65536);  // 4096 f32 (16KB)
    float* out = (float*)d_out;

    pk_all<<<dim3(528), dim3(256), 0, stream>>>(Wvf1, Wvf2, Wm, bm, logsig,
                                                W1F, W2F, A3F, c_all);
    rde_main<<<dim3(32), dim3(512), 0, stream>>>(
        ts, x0, ivls, bvf1, bvf2, Win, bin, Wout, bout,
        W1F, W2F, A3F, c_all, out);
}

// Round 2
// 316.297 us; speedup vs baseline: 1.1957x; 1.1957x over previous
//
#include <hip/hip_runtime.h>

#define YW 136   // f32 elems per Ys row (128 + 8 pad)

typedef _Float16 f16x8 __attribute__((ext_vector_type(8)));
typedef _Float16 f16x4 __attribute__((ext_vector_type(4)));
typedef __attribute__((ext_vector_type(4))) float f32x4;

// 5-op tanh: 1 - 2/(e^{2x}+1). Safe at +/-inf. |err| ~1e-7.
__device__ __forceinline__ float fast_tanh(float x) {
    float e = __expf(2.0f * x);
    return 1.0f - 2.0f / (e + 1.0f);
}
// Workgroup barrier ordering LDS only — does NOT drain vmcnt, so global
// loads issued before it stay in flight across it.
__device__ __forceinline__ void bar_lds() {
    asm volatile("s_waitcnt lgkmcnt(0)\n\ts_barrier" ::: "memory");
}

// Activation planes are stored in MFMA FRAGMENT ORDER: plane[kc][lane][j],
// addr = kc*512 + lane*8 + j halfs, element (row m=lane&15, col kc*32+(lane>>4)*8+j).
// Stage reads are then lane-contiguous 16B (the proven conflict-free pattern).
// fidx maps (row m, col c) -> half index for the commit writes.
__device__ __forceinline__ int fidx(int m, int c) {
    return ((c >> 5) << 9) | (((c >> 3) & 3) << 7) | (m << 3) | (c & 7);
}

// ---------------- fused precompute: weights -> MFMA fragment layout, hi/lo fp16 ----
// F layout: [plane][nt][kc][lane(64)][j(8)]; value = W[n*K+k], n=nt*16+(l&15),
// k=kc*32+(l>>4)*8+j. Same lane formula serves as A- or B-operand fragment.
__global__ __launch_bounds__(256) void pk_all(
    const float* __restrict__ Wvf1, const float* __restrict__ Wvf2,
    const float* __restrict__ Wm,   const float* __restrict__ bm,
    const float* __restrict__ logsig,
    _Float16* __restrict__ W1F, _Float16* __restrict__ W2F,
    _Float16* __restrict__ A3F, float* __restrict__ c_all)
{
    __shared__ float ls[32][62];
    const int b = blockIdx.x, t = threadIdx.x;
    if (b < 128) {                      // W1: N=256 x K=128 (16 nt, 4 kc)
        int u = b * 256 + t;
        int j = u & 7, l = (u >> 3) & 63;
        int kc = (u >> 9) & 3, nt = (u >> 9) >> 2;
        int n = nt * 16 + (l & 15), k = kc * 32 + (l >> 4) * 8 + j;
        float w = Wvf1[n * 128 + k];
        _Float16 hi = (_Float16)w;
        W1F[u] = hi;
        W1F[32768 + u] = (_Float16)(w - (float)hi);
    } else if (b < 384) {               // W2: 256x256 (16 nt, 8 kc)
        int u = (b - 128) * 256 + t;
        int j = u & 7, l = (u >> 3) & 63;
        int kc = (u >> 9) & 7, nt = (u >> 9) >> 3;
        int n = nt * 16 + (l & 15), k = kc * 32 + (l >> 4) * 8 + j;
        float w = Wvf2[n * 256 + k];
        _Float16 hi = (_Float16)w;
        W2F[u] = hi;
        W2F[65536 + u] = (_Float16)(w - (float)hi);
    } else if (b < 896) {               // A_r, r-chunks of 8 (4 chunks x 128 blocks)
        for (int e2 = t; e2 < 32 * 62; e2 += 256)
            ls[e2 / 62][e2 % 62] = logsig[(e2 / 62) * 63 + 1 + (e2 % 62)];
        __syncthreads();
        int idx = b - 384;
        int chunk = idx >> 7;
        int u = (idx & 127) * 256 + t;
        int j = u & 7, l = (u >> 3) & 63, kc = (u >> 9) & 7, nt = (u >> 12) & 7;
        int h = nt * 16 + (l & 15);
        int v = kc * 32 + (l >> 4) * 8 + j;
        int r0 = chunk * 8;
        float acc[8];
#pragma unroll
        for (int r = 0; r < 8; r++) acc[r] = 0.f;
        for (int ll = 0; ll < 62; ll++) {
            float wv2 = Wm[(h * 62 + ll) * 256 + v];
#pragma unroll
            for (int r = 0; r < 8; r++) acc[r] += wv2 * ls[r0 + r][ll];
        }
        for (int r = 0; r < 8; r++) {
            _Float16 hi = (_Float16)acc[r];
            A3F[(r0 + r) * 65536 + u] = hi;
            A3F[(r0 + r) * 65536 + 32768 + u] = (_Float16)(acc[r] - (float)hi);
        }
    } else {                            // c_r[h] = bm[h,:] . seg_r
        int u = (b - 896) * 256 + t;
        int r = u >> 7, h = u & 127;
        float acc = 0.f;
        for (int ll = 0; ll < 62; ll++) acc += bm[h * 62 + ll] * logsig[r * 63 + 1 + ll];
        c_all[u] = acc;
    }
}

// ---------------- main fused kernel: 32 blocks x 16 rows, 8 waves, 20-step Heun ---
// v3: launch_bounds(512,1) unfreezes the 128-VGPR cap (round-1 spilled at 128).
// W1 HI plane in registers (32 VGPR), W1 LO plane in LDS (64 KB).
// Activations ping-pong between two hi/lo FRAGMENT-ORDERED planes: stage reads
// are lane-contiguous 16B (conflict-free); 3 barriers/eval instead of 6.
// Transposed MFMA (weights = A-operand), fp16 hi/lo 3-chain (absmax 0.0039).
__global__ __launch_bounds__(512, 1) void rde_main(
    const float* __restrict__ ts, const float* __restrict__ x0,
    const float* __restrict__ intervals,
    const float* __restrict__ b1g, const float* __restrict__ b2g,
    const float* __restrict__ Win, const float* __restrict__ bin,
    const float* __restrict__ Wout, const float* __restrict__ bout,
    const _Float16* __restrict__ W1F, const _Float16* __restrict__ W2F,
    const _Float16* __restrict__ A3F, const float* __restrict__ c_all,
    float* __restrict__ out)
{
    __shared__ __align__(16) _Float16 W1L[32768];      // 64 KB: W1 lo-plane frags
    __shared__ __align__(16) _Float16 ABUF[4][4096];   // {H0,L0,H1,L1} 8KB each
    __shared__ float Ys[16 * YW];
    __shared__ float ivl[33];
    __shared__ int   r_arr[40];
    __shared__ float s_arr[40];
    __shared__ float lg[16][12];

    const int t    = threadIdx.x;
    const int lane = t & 63;
    const int wv   = t >> 6;        // wave 0..7
    const int m16  = lane & 15;     // batch row within tile
    const int q    = lane >> 4;
    const int row0 = blockIdx.x * 16;

    // W1 hi fragments -> registers (32 VGPR, coalesced 16B/lane); lo -> LDS
    f16x8 w1h[2][4];
#pragma unroll
    for (int tt = 0; tt < 2; tt++)
#pragma unroll
        for (int kc = 0; kc < 4; kc++)
            w1h[tt][kc] = *(const f16x8*)(W1F + ((wv * 8 + tt * 4 + kc) * 64 + lane) * 8);
    for (int e2 = t; e2 < 4096; e2 += 512)
        ((uint4*)W1L)[e2] = ((const uint4*)(W1F + 32768))[e2];

    if (t < 33) ivl[t] = intervals[t];
    __syncthreads();

    const float ts0 = ts[0];
    const float dt  = __fdiv_rn(ts[32] - ts0, 20.0f);   // bit-exact vs reference

    if (t < 40) {   // searchsorted idx + 1/delta for all 40 VF evals
        int i = t >> 1;
        float tv = ts0 + (float)i * dt;
        if (t & 1) tv += dt;
        int p = 0;
        for (int j2 = 0; j2 < 32; j2++) p += (ivl[1 + j2] < tv) ? 1 : 0;
        int idx = p + 1;
        idx = idx < 1 ? 1 : idx;
        idx = idx > 32 ? 32 : idx;
        r_arr[t] = idx - 1;
        s_arr[t] = __fdiv_rn(1.0f, ivl[idx] - ivl[idx - 1]);
    }

    // biases along D rows (q*4+r) for this wave's stage1/2 n-tiles wv*2, wv*2+1
    f32x4 b1f[2], b2f[2];
#pragma unroll
    for (int tt = 0; tt < 2; tt++) {
        b1f[tt] = *(const f32x4*)(b1g + (wv * 2 + tt) * 16 + q * 4);
        b2f[tt] = *(const f32x4*)(b2g + (wv * 2 + tt) * 16 + q * 4);
    }

    // y0 = x0 @ Win.T + bin -> Y regs + buf0 (stage3 D layout: rows q*4+r, col wv*16+m16)
    float Y[4], K1[4];
    {
        const float* xr = x0 + (row0 + m16) * 5;
        float xv[5];
#pragma unroll
        for (int d = 0; d < 5; d++) xv[d] = xr[d];
        int c0 = wv * 16 + q * 4;
        f16x4 hv, lv;
#pragma unroll
        for (int r = 0; r < 4; r++) {
            float acc = bin[c0 + r];
#pragma unroll
            for (int d = 0; d < 5; d++) acc += xv[d] * Win[(c0 + r) * 5 + d];
            Y[r] = acc;
            K1[r] = 0.f;
            _Float16 hi = (_Float16)acc;
            hv[r] = hi;
            lv[r] = (_Float16)(acc - (float)hi);
        }
        *(f16x4*)(ABUF[0] + fidx(m16, c0)) = hv;    // 512 thr x 4 = full 16x128
        *(f16x4*)(ABUF[1] + fidx(m16, c0)) = lv;
    }
    __syncthreads();

    // One VF eval. pb/qb are compile-time after inlining -> static LDS indexing.
    // S1: read P(y) write Q(h1); bar; S2: read Q write P(h2); bar; S3: read P,
    // Heun-commit y' -> Q; bar. Writes always target a buffer whose readers
    // all passed the previous barrier.
    auto EVAL = [&](int e, int half, int pb, int qb) {
        const int ri   = r_arr[e];
        const float s  = s_arr[e];
        const _Float16* ABase = A3F + ri * 65536;
        _Float16* Ph = ABUF[pb];
        _Float16* Pl = ABUF[pb + 1];
        _Float16* Qh = ABUF[qb];
        _Float16* Ql = ABUF[qb + 1];

        // ---- stage1: h1 = relu(W1 . y), K=128; W1 hi regs, lo LDS ----
        // issue W2 window A (kc 0..3) first — in flight across all of stage1
        f16x8 w2a[2][4][2];
#pragma unroll
        for (int tt = 0; tt < 2; tt++)
#pragma unroll
            for (int kc = 0; kc < 4; kc++) {
                const _Float16* bp = W2F + ((wv * 16 + tt * 8 + kc) * 64 + lane) * 8;
                w2a[tt][kc][0] = *(const f16x8*)bp;
                w2a[tt][kc][1] = *(const f16x8*)(bp + 65536);
            }
        f32x4 aA[2], aB[2], aC[2];
#pragma unroll
        for (int tt = 0; tt < 2; tt++) {
            aA[tt] = b1f[tt];
            aB[tt] = (f32x4){0.f, 0.f, 0.f, 0.f};
            aC[tt] = (f32x4){0.f, 0.f, 0.f, 0.f};
        }
#pragma unroll
        for (int kc = 0; kc < 4; kc++) {
            f16x8 ah = *(const f16x8*)(Ph + kc * 512 + lane * 8);
            f16x8 al = *(const f16x8*)(Pl + kc * 512 + lane * 8);
#pragma unroll
            for (int tt = 0; tt < 2; tt++) {
                f16x8 bl = *(const f16x8*)(W1L + (wv * 8 + tt * 4 + kc) * 512 + lane * 8);
                aA[tt] = __builtin_amdgcn_mfma_f32_16x16x32_f16(w1h[tt][kc], ah, aA[tt], 0, 0, 0);
                aB[tt] = __builtin_amdgcn_mfma_f32_16x16x32_f16(bl, ah, aB[tt], 0, 0, 0);
                aC[tt] = __builtin_amdgcn_mfma_f32_16x16x32_f16(w1h[tt][kc], al, aC[tt], 0, 0, 0);
            }
        }
#pragma unroll
        for (int tt = 0; tt < 2; tt++) {        // commit h1 -> Q, packed b64
            int n0 = (wv * 2 + tt) * 16 + q * 4;
            f16x4 hv, lv;
#pragma unroll
            for (int r = 0; r < 4; r++) {       // D: col=lane&15 (m), row=q*4+r (n)
                float v = fmaxf(aA[tt][r] + aB[tt][r] + aC[tt][r], 0.f);
                _Float16 hi = (_Float16)v;
                hv[r] = hi;
                lv[r] = (_Float16)(v - (float)hi);
            }
            *(f16x4*)(Qh + fidx(m16, n0)) = hv;
            *(f16x4*)(Ql + fidx(m16, n0)) = lv;
        }
        bar_lds();

        // ---- stage2: h2 = tanh(W2 . h1), K=256; w2a preloaded, w2b issued now ----
        f16x8 w2b[2][4][2];
#pragma unroll
        for (int tt = 0; tt < 2; tt++)
#pragma unroll
            for (int kc = 0; kc < 4; kc++) {
                const _Float16* bp = W2F + ((wv * 16 + tt * 8 + 4 + kc) * 64 + lane) * 8;
                w2b[tt][kc][0] = *(const f16x8*)bp;
                w2b[tt][kc][1] = *(const f16x8*)(bp + 65536);
            }
#pragma unroll
        for (int tt = 0; tt < 2; tt++) {
            aA[tt] = b2f[tt];
            aB[tt] = (f32x4){0.f, 0.f, 0.f, 0.f};
            aC[tt] = (f32x4){0.f, 0.f, 0.f, 0.f};
        }
#pragma unroll
        for (int kc = 0; kc < 4; kc++) {        // first half with w2a
            f16x8 ah = *(const f16x8*)(Qh + kc * 512 + lane * 8);
            f16x8 al = *(const f16x8*)(Ql + kc * 512 + lane * 8);
#pragma unroll
            for (int tt = 0; tt < 2; tt++) {
                aA[tt] = __builtin_amdgcn_mfma_f32_16x16x32_f16(w2a[tt][kc][0], ah, aA[tt], 0, 0, 0);
                aB[tt] = __builtin_amdgcn_mfma_f32_16x16x32_f16(w2a[tt][kc][1], ah, aB[tt], 0, 0, 0);
                aC[tt] = __builtin_amdgcn_mfma_f32_16x16x32_f16(w2a[tt][kc][0], al, aC[tt], 0, 0, 0);
            }
        }
        // issue A_r window A (kc 0..3; stage3 n-tile = wv) + c vector
        f16x8 a3a[4][2];
#pragma unroll
        for (int kc = 0; kc < 4; kc++) {
            const _Float16* bp = ABase + ((wv * 8 + kc) * 64 + lane) * 8;
            a3a[kc][0] = *(const f16x8*)bp;
            a3a[kc][1] = *(const f16x8*)(bp + 32768);
        }
        f32x4 cf = *(const f32x4*)(c_all + ri * 128 + wv * 16 + q * 4);
#pragma unroll
        for (int kc = 0; kc < 4; kc++) {        // second half with w2b
            f16x8 ah = *(const f16x8*)(Qh + (4 + kc) * 512 + lane * 8);
            f16x8 al = *(const f16x8*)(Ql + (4 + kc) * 512 + lane * 8);
#pragma unroll
            for (int tt = 0; tt < 2; tt++) {
                aA[tt] = __builtin_amdgcn_mfma_f32_16x16x32_f16(w2b[tt][kc][0], ah, aA[tt], 0, 0, 0);
                aB[tt] = __builtin_amdgcn_mfma_f32_16x16x32_f16(w2b[tt][kc][1], ah, aB[tt], 0, 0, 0);
                aC[tt] = __builtin_amdgcn_mfma_f32_16x16x32_f16(w2b[tt][kc][0], al, aC[tt], 0, 0, 0);
            }
        }
        // issue A_r window B (kc 4..7)
        f16x8 a3b[4][2];
#pragma unroll
        for (int kc = 0; kc < 4; kc++) {
            const _Float16* bp = ABase + ((wv * 8 + 4 + kc) * 64 + lane) * 8;
            a3b[kc][0] = *(const f16x8*)bp;
            a3b[kc][1] = *(const f16x8*)(bp + 32768);
        }
#pragma unroll
        for (int tt = 0; tt < 2; tt++) {        // commit h2 (tanh) -> P
            int n0 = (wv * 2 + tt) * 16 + q * 4;
            f16x4 hv, lv;
#pragma unroll
            for (int r = 0; r < 4; r++) {
                float v = fast_tanh(aA[tt][r] + aB[tt][r] + aC[tt][r]);
                _Float16 hi = (_Float16)v;
                hv[r] = hi;
                lv[r] = (_Float16)(v - (float)hi);
            }
            *(f16x4*)(Ph + fidx(m16, n0)) = hv;
            *(f16x4*)(Pl + fidx(m16, n0)) = lv;
        }
        bar_lds();

        // ---- stage3: k = (A_r . h2 + c) * s ----
        f32x4 kA = cf;
        f32x4 kB = (f32x4){0.f, 0.f, 0.f, 0.f};
        f32x4 kC = (f32x4){0.f, 0.f, 0.f, 0.f};
#pragma unroll
        for (int kc = 0; kc < 4; kc++) {        // kc 0..3 with a3a
            f16x8 ah = *(const f16x8*)(Ph + kc * 512 + lane * 8);
            f16x8 al = *(const f16x8*)(Pl + kc * 512 + lane * 8);
            kA = __builtin_amdgcn_mfma_f32_16x16x32_f16(a3a[kc][0], ah, kA, 0, 0, 0);
            kB = __builtin_amdgcn_mfma_f32_16x16x32_f16(a3a[kc][1], ah, kB, 0, 0, 0);
            kC = __builtin_amdgcn_mfma_f32_16x16x32_f16(a3a[kc][0], al, kC, 0, 0, 0);
        }
#pragma unroll
        for (int kc = 0; kc < 4; kc++) {        // kc 4..7 with a3b
            f16x8 ah = *(const f16x8*)(Ph + (4 + kc) * 512 + lane * 8);
            f16x8 al = *(const f16x8*)(Pl + (4 + kc) * 512 + lane * 8);
            kA = __builtin_amdgcn_mfma_f32_16x16x32_f16(a3b[kc][0], ah, kA, 0, 0, 0);
            kB = __builtin_amdgcn_mfma_f32_16x16x32_f16(a3b[kc][1], ah, kB, 0, 0, 0);
            kC = __builtin_amdgcn_mfma_f32_16x16x32_f16(a3b[kc][0], al, kC, 0, 0, 0);
        }
        {                                       // Heun commit + y' -> Q
            int c0 = wv * 16 + q * 4;
            f16x4 hv, lv;
#pragma unroll
            for (int r = 0; r < 4; r++) {
                float kv = (kA[r] + kB[r] + kC[r]) * s;
                float yn;
                if (half == 0) {                 // k1: stash, form y+dt*k1
                    K1[r] = kv;
                    yn = Y[r] + dt * kv;
                } else {                         // k2: y += 0.5*dt*(k1+k2)
                    yn = Y[r] + 0.5f * dt * (K1[r] + kv);
                    Y[r] = yn;
                }
                _Float16 hi = (_Float16)yn;
                hv[r] = hi;
                lv[r] = (_Float16)(yn - (float)hi);
            }
            *(f16x4*)(Qh + fidx(m16, c0)) = hv;
            *(f16x4*)(Ql + fidx(m16, c0)) = lv;
        }
        bar_lds();
    };

#pragma unroll 1
    for (int e2 = 0; e2 < 20; e2++) {
        EVAL(2 * e2,     0, 0, 2);   // y in buf0 -> y' in buf1
        EVAL(2 * e2 + 1, 1, 2, 0);   // y in buf1 -> y' in buf0
    }

    // epilogue: Y regs -> Ys f32 [m][h]
#pragma unroll
    for (int r = 0; r < 4; r++)
        Ys[m16 * YW + wv * 16 + q * 4 + r] = Y[r];
    __syncthreads();
    if (t < 160) {                  // logits
        int m = t / 10, c = t % 10;
        float acc = bout[c];
        for (int k = 0; k < 128; k++) acc += Ys[m * YW + k] * Wout[c * 128 + k];
        lg[m][c] = acc;
    }
    __syncthreads();
    if (t < 16) {                   // softmax
        float mx = -1e30f;
#pragma unroll
        for (int c = 0; c < 10; c++) mx = fmaxf(mx, lg[t][c]);
        float ex[10], sum = 0.f;
#pragma unroll
        for (int c = 0; c < 10; c++) { ex[c] = expf(lg[t][c] - mx); sum += ex[c]; }
        float inv = __fdiv_rn(1.0f, sum);
#pragma unroll
        for (int c = 0; c < 10; c++) out[(row0 + t) * 10 + c] = ex[c] * inv;
    }
}

extern "C" void kernel_launch(void* const* d_in, const int* in_sizes, int n_in,
                              void* d_out, int out_size, void* d_ws, size_t ws_size,
                              hipStream_t stream) {
    const float* ts     = (const float*)d_in[0];
    const float* logsig = (const float*)d_in[1];
    const float* x0     = (const float*)d_in[2];
    const float* ivls   = (const float*)d_in[3];
    const float* Wvf1   = (const float*)d_in[4];
    const float* bvf1   = (const float*)d_in[5];
    const float* Wvf2   = (const float*)d_in[6];
    const float* bvf2   = (const float*)d_in[7];
    const float* Wm     = (const float*)d_in[8];
    const float* bm     = (const float*)d_in[9];
    const float* Win    = (const float*)d_in[10];
    const float* bin    = (const float*)d_in[11];
    const float* Wout   = (const float*)d_in[12];
    const float* bout   = (const float*)d_in[13];

    _Float16* W1F = (_Float16*)d_ws;            // 65536 halfs (128KB, hi+lo)
    _Float16* W2F = W1F + 65536;                // 131072 halfs (256KB, hi+lo)
    _Float16* A3F = W2F + 131072;               // 32*65536 halfs (4MB, hi+lo per r)
    float* c_all = (float*)(A3F + 32 * 65536);  // 4096 f32 (16KB)
    float* out = (float*)d_out;

    pk_all<<<dim3(912), dim3(256), 0, stream>>>(Wvf1, Wvf2, Wm, bm, logsig,
                                                W1F, W2F, A3F, c_all);
    rde_main<<<dim3(32), dim3(512), 0, stream>>>(
        ts, x0, ivls, bvf1, bvf2, Win, bin, Wout, bout,
        W1F, W2F, A3F, c_all, out);
}

// Round 3
// 254.175 us; speedup vs baseline: 1.4880x; 1.2444x over previous
//
#include <hip/hip_runtime.h>

#define YW 136   // f32 elems per Ys row (128 + 8 pad)

typedef _Float16 f16x8 __attribute__((ext_vector_type(8)));
typedef _Float16 f16x4 __attribute__((ext_vector_type(4)));
typedef __attribute__((ext_vector_type(4))) float f32x4;

// 5-op tanh: 1 - 2/(e^{2x}+1). Safe at +/-inf. |err| ~1e-7.
__device__ __forceinline__ float fast_tanh(float x) {
    float e = __expf(2.0f * x);
    return 1.0f - 2.0f / (e + 1.0f);
}
// Workgroup barrier ordering LDS only — does NOT drain vmcnt, so global
// loads issued before it stay in flight across it.
__device__ __forceinline__ void bar_lds() {
    asm volatile("s_waitcnt lgkmcnt(0)\n\ts_barrier" ::: "memory");
}

// Activation planes are stored in MFMA FRAGMENT ORDER: plane[kc][lane][j],
// addr = kc*512 + lane*8 + j halfs, element (row m=lane&15, col kc*32+(lane>>4)*8+j).
// Stage reads are then lane-contiguous 16B (the proven conflict-free pattern,
// round-2: bank conflicts 2.05M -> 0.41M). fidx maps (row m, col c) -> half idx
// for commit writes.
__device__ __forceinline__ int fidx(int m, int c) {
    return ((c >> 5) << 9) | (((c >> 3) & 3) << 7) | (m << 3) | (c & 7);
}

// ---------------- fused precompute: weights -> MFMA fragment layout, hi/lo fp16 ----
// F layout: [plane][nt][kc][lane(64)][j(8)]; value = W[n*K+k], n=nt*16+(l&15),
// k=kc*32+(l>>4)*8+j. Same lane formula serves as A- or B-operand fragment.
__global__ __launch_bounds__(256) void pk_all(
    const float* __restrict__ Wvf1, const float* __restrict__ Wvf2,
    const float* __restrict__ Wm,   const float* __restrict__ bm,
    const float* __restrict__ logsig,
    _Float16* __restrict__ W1F, _Float16* __restrict__ W2F,
    _Float16* __restrict__ A3F, float* __restrict__ c_all)
{
    __shared__ float ls[32][62];
    const int b = blockIdx.x, t = threadIdx.x;
    if (b < 128) {                      // W1: N=256 x K=128 (16 nt, 4 kc)
        int u = b * 256 + t;
        int j = u & 7, l = (u >> 3) & 63;
        int kc = (u >> 9) & 3, nt = (u >> 9) >> 2;
        int n = nt * 16 + (l & 15), k = kc * 32 + (l >> 4) * 8 + j;
        float w = Wvf1[n * 128 + k];
        _Float16 hi = (_Float16)w;
        W1F[u] = hi;
        W1F[32768 + u] = (_Float16)(w - (float)hi);
    } else if (b < 384) {               // W2: 256x256 (16 nt, 8 kc)
        int u = (b - 128) * 256 + t;
        int j = u & 7, l = (u >> 3) & 63;
        int kc = (u >> 9) & 7, nt = (u >> 9) >> 3;
        int n = nt * 16 + (l & 15), k = kc * 32 + (l >> 4) * 8 + j;
        float w = Wvf2[n * 256 + k];
        _Float16 hi = (_Float16)w;
        W2F[u] = hi;
        W2F[65536 + u] = (_Float16)(w - (float)hi);
    } else if (b < 896) {               // A_r, r-chunks of 8 (4 chunks x 128 blocks)
        for (int e2 = t; e2 < 32 * 62; e2 += 256)
            ls[e2 / 62][e2 % 62] = logsig[(e2 / 62) * 63 + 1 + (e2 % 62)];
        __syncthreads();
        int idx = b - 384;
        int chunk = idx >> 7;
        int u = (idx & 127) * 256 + t;
        int j = u & 7, l = (u >> 3) & 63, kc = (u >> 9) & 7, nt = (u >> 12) & 7;
        int h = nt * 16 + (l & 15);
        int v = kc * 32 + (l >> 4) * 8 + j;
        int r0 = chunk * 8;
        float acc[8];
#pragma unroll
        for (int r = 0; r < 8; r++) acc[r] = 0.f;
        // full unroll: 62 independent Wm loads pipeline instead of serializing
#pragma unroll
        for (int ll = 0; ll < 62; ll++) {
            float wv2 = Wm[(h * 62 + ll) * 256 + v];
#pragma unroll
            for (int r = 0; r < 8; r++) acc[r] += wv2 * ls[r0 + r][ll];
        }
#pragma unroll
        for (int r = 0; r < 8; r++) {
            _Float16 hi = (_Float16)acc[r];
            A3F[(r0 + r) * 65536 + u] = hi;
            A3F[(r0 + r) * 65536 + 32768 + u] = (_Float16)(acc[r] - (float)hi);
        }
    } else {                            // c_r[h] = bm[h,:] . seg_r
        int u = (b - 896) * 256 + t;
        int r = u >> 7, h = u & 127;
        float acc = 0.f;
#pragma unroll
        for (int ll = 0; ll < 62; ll++) acc += bm[h * 62 + ll] * logsig[r * 63 + 1 + ll];
        c_all[u] = acc;
    }
}

// ---------------- main fused kernel: 32 blocks x 16 rows, 8 waves, 20-step Heun ---
// v4: round-0 register profile (W1 hi+lo in LDS, no lambda, launch_bounds(512,2)
// -> proven 128 VGPR / zero spill) + fragment-ordered activation planes (proven
// conflict fix) + 4-barrier schedule: separate Y plane (16x128) and one H plane
// (16x256). S1: Y->H (1 bar); S2: H->H in-place (read-all bar + commit bar);
// S3: H->Y (1 bar). Epilogue Ys/lg overlay the dead H plane.
// Transposed MFMA (weights = A-operand), fp16 hi/lo 3-chain (absmax 0.0039).
__global__ __launch_bounds__(512, 2) void rde_main(
    const float* __restrict__ ts, const float* __restrict__ x0,
    const float* __restrict__ intervals,
    const float* __restrict__ b1g, const float* __restrict__ b2g,
    const float* __restrict__ Win, const float* __restrict__ bin,
    const float* __restrict__ Wout, const float* __restrict__ bout,
    const _Float16* __restrict__ W1F, const _Float16* __restrict__ W2F,
    const _Float16* __restrict__ A3F, const float* __restrict__ c_all,
    float* __restrict__ out)
{
    __shared__ __align__(16) _Float16 W1s[65536];      // 128 KB hi+lo
    __shared__ __align__(16) _Float16 HBUF[2][4096];   // H plane hi/lo, 16 KB
    __shared__ __align__(16) _Float16 YBUF[2][2048];   // Y plane hi/lo, 8 KB
    __shared__ float ivl[33];
    __shared__ int   r_arr[40];
    __shared__ float s_arr[40];

    _Float16* Hh = HBUF[0];
    _Float16* Hl = HBUF[1];
    _Float16* Yh = YBUF[0];
    _Float16* Yl = YBUF[1];

    const int t    = threadIdx.x;
    const int lane = t & 63;
    const int wv   = t >> 6;        // wave 0..7
    const int m16  = lane & 15;     // batch row within tile
    const int q    = lane >> 4;
    const int row0 = blockIdx.x * 16;

    if (t < 33) ivl[t] = intervals[t];
    // W1 hi+lo -> LDS once: 65536 halfs = 8192 uint4
    for (int e2 = t; e2 < 8192; e2 += 512)
        ((uint4*)W1s)[e2] = ((const uint4*)W1F)[e2];
    __syncthreads();

    const float ts0 = ts[0];
    const float dt  = __fdiv_rn(ts[32] - ts0, 20.0f);   // bit-exact vs reference

    if (t < 40) {   // searchsorted idx + 1/delta for all 40 VF evals
        int i = t >> 1;
        float tv = ts0 + (float)i * dt;
        if (t & 1) tv += dt;
        int p = 0;
        for (int j2 = 0; j2 < 32; j2++) p += (ivl[1 + j2] < tv) ? 1 : 0;
        int idx = p + 1;
        idx = idx < 1 ? 1 : idx;
        idx = idx > 32 ? 32 : idx;
        r_arr[t] = idx - 1;
        s_arr[t] = __fdiv_rn(1.0f, ivl[idx] - ivl[idx - 1]);
    }

    // biases along D rows (q*4+r) for this wave's stage1/2 n-tiles wv*2, wv*2+1
    f32x4 b1f[2], b2f[2];
#pragma unroll
    for (int tt = 0; tt < 2; tt++) {
        b1f[tt] = *(const f32x4*)(b1g + (wv * 2 + tt) * 16 + q * 4);
        b2f[tt] = *(const f32x4*)(b2g + (wv * 2 + tt) * 16 + q * 4);
    }

    // y0 = x0 @ Win.T + bin -> Y regs + Y plane (stage3 D layout: rows q*4+r, col wv*16+m16)
    float Y[4], K1[4];
    {
        const float* xr = x0 + (row0 + m16) * 5;
        float xv[5];
#pragma unroll
        for (int d = 0; d < 5; d++) xv[d] = xr[d];
        int c0 = wv * 16 + q * 4;
        f16x4 hv, lv;
#pragma unroll
        for (int r = 0; r < 4; r++) {
            float acc = bin[c0 + r];
#pragma unroll
            for (int d = 0; d < 5; d++) acc += xv[d] * Win[(c0 + r) * 5 + d];
            Y[r] = acc;
            K1[r] = 0.f;
            _Float16 hi = (_Float16)acc;
            hv[r] = hi;
            lv[r] = (_Float16)(acc - (float)hi);
        }
        *(f16x4*)(Yh + fidx(m16, c0)) = hv;    // 512 thr x 4 = full 16x128
        *(f16x4*)(Yl + fidx(m16, c0)) = lv;
    }
    __syncthreads();

#pragma unroll 1
    for (int e = 0; e < 40; e++) {
        const int half = e & 1;
        const int ri   = r_arr[e];
        const float s  = s_arr[e];
        const _Float16* ABase = A3F + ri * 65536;

        // ---- stage1: h1 = relu(W1 . y), K=128; W1 frags from LDS ----
        // issue W2 window A (kc 0..3) first — in flight across all of stage1
        f16x8 w2a[2][4][2];
#pragma unroll
        for (int tt = 0; tt < 2; tt++)
#pragma unroll
            for (int kc = 0; kc < 4; kc++) {
                const _Float16* bp = W2F + ((wv * 16 + tt * 8 + kc) * 64 + lane) * 8;
                w2a[tt][kc][0] = *(const f16x8*)bp;
                w2a[tt][kc][1] = *(const f16x8*)(bp + 65536);
            }
        f32x4 aA[2], aB[2], aC[2];
#pragma unroll
        for (int tt = 0; tt < 2; tt++) {
            aA[tt] = b1f[tt];
            aB[tt] = (f32x4){0.f, 0.f, 0.f, 0.f};
            aC[tt] = (f32x4){0.f, 0.f, 0.f, 0.f};
        }
#pragma unroll
        for (int kc = 0; kc < 4; kc++) {
            f16x8 ah = *(const f16x8*)(Yh + kc * 512 + lane * 8);
            f16x8 al = *(const f16x8*)(Yl + kc * 512 + lane * 8);
#pragma unroll
            for (int tt = 0; tt < 2; tt++) {
                int wb = ((wv * 8 + tt * 4 + kc) * 64 + lane) * 8;
                f16x8 bh = *(const f16x8*)(W1s + wb);
                f16x8 bl = *(const f16x8*)(W1s + 32768 + wb);
                aA[tt] = __builtin_amdgcn_mfma_f32_16x16x32_f16(bh, ah, aA[tt], 0, 0, 0);
                aB[tt] = __builtin_amdgcn_mfma_f32_16x16x32_f16(bl, ah, aB[tt], 0, 0, 0);
                aC[tt] = __builtin_amdgcn_mfma_f32_16x16x32_f16(bh, al, aC[tt], 0, 0, 0);
            }
        }
#pragma unroll
        for (int tt = 0; tt < 2; tt++) {        // commit h1 -> H plane (fresh buffer)
            int n0 = (wv * 2 + tt) * 16 + q * 4;
            f16x4 hv, lv;
#pragma unroll
            for (int r = 0; r < 4; r++) {       // D: col=lane&15 (m), row=q*4+r (n)
                float v = fmaxf(aA[tt][r] + aB[tt][r] + aC[tt][r], 0.f);
                _Float16 hi = (_Float16)v;
                hv[r] = hi;
                lv[r] = (_Float16)(v - (float)hi);
            }
            *(f16x4*)(Hh + fidx(m16, n0)) = hv;
            *(f16x4*)(Hl + fidx(m16, n0)) = lv;
        }
        bar_lds();                              // (1) h1 visible

        // ---- stage2: h2 = tanh(W2 . h1), K=256; w2a preloaded, w2b issued now ----
        f16x8 w2b[2][4][2];
#pragma unroll
        for (int tt = 0; tt < 2; tt++)
#pragma unroll
            for (int kc = 0; kc < 4; kc++) {
                const _Float16* bp = W2F + ((wv * 16 + tt * 8 + 4 + kc) * 64 + lane) * 8;
                w2b[tt][kc][0] = *(const f16x8*)bp;
                w2b[tt][kc][1] = *(const f16x8*)(bp + 65536);
            }
#pragma unroll
        for (int tt = 0; tt < 2; tt++) {
            aA[tt] = b2f[tt];
            aB[tt] = (f32x4){0.f, 0.f, 0.f, 0.f};
            aC[tt] = (f32x4){0.f, 0.f, 0.f, 0.f};
        }
#pragma unroll
        for (int kc = 0; kc < 4; kc++) {        // first half with w2a
            f16x8 ah = *(const f16x8*)(Hh + kc * 512 + lane * 8);
            f16x8 al = *(const f16x8*)(Hl + kc * 512 + lane * 8);
#pragma unroll
            for (int tt = 0; tt < 2; tt++) {
                aA[tt] = __builtin_amdgcn_mfma_f32_16x16x32_f16(w2a[tt][kc][0], ah, aA[tt], 0, 0, 0);
                aB[tt] = __builtin_amdgcn_mfma_f32_16x16x32_f16(w2a[tt][kc][1], ah, aB[tt], 0, 0, 0);
                aC[tt] = __builtin_amdgcn_mfma_f32_16x16x32_f16(w2a[tt][kc][0], al, aC[tt], 0, 0, 0);
            }
        }
        // issue A_r window A (kc 0..3; stage3 n-tile = wv) + c vector
        f16x8 a3a[4][2];
#pragma unroll
        for (int kc = 0; kc < 4; kc++) {
            const _Float16* bp = ABase + ((wv * 8 + kc) * 64 + lane) * 8;
            a3a[kc][0] = *(const f16x8*)bp;
            a3a[kc][1] = *(const f16x8*)(bp + 32768);
        }
        f32x4 cf = *(const f32x4*)(c_all + ri * 128 + wv * 16 + q * 4);
#pragma unroll
        for (int kc = 0; kc < 4; kc++) {        // second half with w2b
            f16x8 ah = *(const f16x8*)(Hh + (4 + kc) * 512 + lane * 8);
            f16x8 al = *(const f16x8*)(Hl + (4 + kc) * 512 + lane * 8);
#pragma unroll
            for (int tt = 0; tt < 2; tt++) {
                aA[tt] = __builtin_amdgcn_mfma_f32_16x16x32_f16(w2b[tt][kc][0], ah, aA[tt], 0, 0, 0);
                aB[tt] = __builtin_amdgcn_mfma_f32_16x16x32_f16(w2b[tt][kc][1], ah, aB[tt], 0, 0, 0);
                aC[tt] = __builtin_amdgcn_mfma_f32_16x16x32_f16(w2b[tt][kc][0], al, aC[tt], 0, 0, 0);
            }
        }
        // issue A_r window B (kc 4..7)
        f16x8 a3b[4][2];
#pragma unroll
        for (int kc = 0; kc < 4; kc++) {
            const _Float16* bp = ABase + ((wv * 8 + 4 + kc) * 64 + lane) * 8;
            a3b[kc][0] = *(const f16x8*)bp;
            a3b[kc][1] = *(const f16x8*)(bp + 32768);
        }
        bar_lds();                              // (2) all h1 reads done
#pragma unroll
        for (int tt = 0; tt < 2; tt++) {        // commit h2 (tanh) in-place -> H
            int n0 = (wv * 2 + tt) * 16 + q * 4;
            f16x4 hv, lv;
#pragma unroll
            for (int r = 0; r < 4; r++) {
                float v = fast_tanh(aA[tt][r] + aB[tt][r] + aC[tt][r]);
                _Float16 hi = (_Float16)v;
                hv[r] = hi;
                lv[r] = (_Float16)(v - (float)hi);
            }
            *(f16x4*)(Hh + fidx(m16, n0)) = hv;
            *(f16x4*)(Hl + fidx(m16, n0)) = lv;
        }
        bar_lds();                              // (3) h2 visible

        // ---- stage3: k = (A_r . h2 + c) * s ----
        f32x4 kA = cf;
        f32x4 kB = (f32x4){0.f, 0.f, 0.f, 0.f};
        f32x4 kC = (f32x4){0.f, 0.f, 0.f, 0.f};
#pragma unroll
        for (int kc = 0; kc < 4; kc++) {        // kc 0..3 with a3a
            f16x8 ah = *(const f16x8*)(Hh + kc * 512 + lane * 8);
            f16x8 al = *(const f16x8*)(Hl + kc * 512 + lane * 8);
            kA = __builtin_amdgcn_mfma_f32_16x16x32_f16(a3a[kc][0], ah, kA, 0, 0, 0);
            kB = __builtin_amdgcn_mfma_f32_16x16x32_f16(a3a[kc][1], ah, kB, 0, 0, 0);
            kC = __builtin_amdgcn_mfma_f32_16x16x32_f16(a3a[kc][0], al, kC, 0, 0, 0);
        }
#pragma unroll
        for (int kc = 0; kc < 4; kc++) {        // kc 4..7 with a3b
            f16x8 ah = *(const f16x8*)(Hh + (4 + kc) * 512 + lane * 8);
            f16x8 al = *(const f16x8*)(Hl + (4 + kc) * 512 + lane * 8);
            kA = __builtin_amdgcn_mfma_f32_16x16x32_f16(a3b[kc][0], ah, kA, 0, 0, 0);
            kB = __builtin_amdgcn_mfma_f32_16x16x32_f16(a3b[kc][1], ah, kB, 0, 0, 0);
            kC = __builtin_amdgcn_mfma_f32_16x16x32_f16(a3b[kc][0], al, kC, 0, 0, 0);
        }
        {                                       // Heun commit + y' -> Y plane
            int c0 = wv * 16 + q * 4;
            f16x4 hv, lv;
#pragma unroll
            for (int r = 0; r < 4; r++) {
                float kv = (kA[r] + kB[r] + kC[r]) * s;
                float yn;
                if (half == 0) {                 // k1: stash, form y+dt*k1
                    K1[r] = kv;
                    yn = Y[r] + dt * kv;
                } else {                         // k2: y += 0.5*dt*(k1+k2)
                    yn = Y[r] + 0.5f * dt * (K1[r] + kv);
                    Y[r] = yn;
                }
                _Float16 hi = (_Float16)yn;
                hv[r] = hi;
                lv[r] = (_Float16)(yn - (float)hi);
            }
            *(f16x4*)(Yh + fidx(m16, c0)) = hv;
            *(f16x4*)(Yl + fidx(m16, c0)) = lv;
        }
        bar_lds();                              // (4) y' visible; H free for next S1
    }

    // epilogue: overlay Ys (16xYW f32) and lg onto the dead H plane (16 KB)
    float* Ys  = (float*)&HBUF[0][0];           // 8704 B
    float* lgp = (float*)&HBUF[0][0] + 16 * YW; // 768 B, still within 16 KB
#pragma unroll
    for (int r = 0; r < 4; r++)
        Ys[m16 * YW + wv * 16 + q * 4 + r] = Y[r];
    __syncthreads();
    if (t < 160) {                  // logits
        int m = t / 10, c = t % 10;
        float acc = bout[c];
        for (int k = 0; k < 128; k++) acc += Ys[m * YW + k] * Wout[c * 128 + k];
        lgp[m * 10 + c] = acc;
    }
    __syncthreads();
    if (t < 16) {                   // softmax
        float mx = -1e30f;
#pragma unroll
        for (int c = 0; c < 10; c++) mx = fmaxf(mx, lgp[t * 10 + c]);
        float ex[10], sum = 0.f;
#pragma unroll
        for (int c = 0; c < 10; c++) { ex[c] = expf(lgp[t * 10 + c] - mx); sum += ex[c]; }
        float inv = __fdiv_rn(1.0f, sum);
#pragma unroll
        for (int c = 0; c < 10; c++) out[(row0 + t) * 10 + c] = ex[c] * inv;
    }
}

extern "C" void kernel_launch(void* const* d_in, const int* in_sizes, int n_in,
                              void* d_out, int out_size, void* d_ws, size_t ws_size,
                              hipStream_t stream) {
    const float* ts     = (const float*)d_in[0];
    const float* logsig = (const float*)d_in[1];
    const float* x0     = (const float*)d_in[2];
    const float* ivls   = (const float*)d_in[3];
    const float* Wvf1   = (const float*)d_in[4];
    const float* bvf1   = (const float*)d_in[5];
    const float* Wvf2   = (const float*)d_in[6];
    const float* bvf2   = (const float*)d_in[7];
    const float* Wm     = (const float*)d_in[8];
    const float* bm     = (const float*)d_in[9];
    const float* Win    = (const float*)d_in[10];
    const float* bin    = (const float*)d_in[11];
    const float* Wout   = (const float*)d_in[12];
    const float* bout   = (const float*)d_in[13];

    _Float16* W1F = (_Float16*)d_ws;            // 65536 halfs (128KB, hi+lo)
    _Float16* W2F = W1F + 65536;                // 131072 halfs (256KB, hi+lo)
    _Float16* A3F = W2F + 131072;               // 32*65536 halfs (4MB, hi+lo per r)
    float* c_all = (float*)(A3F + 32 * 65536);  // 4096 f32 (16KB)
    float* out = (float*)d_out;

    pk_all<<<dim3(912), dim3(256), 0, stream>>>(Wvf1, Wvf2, Wm, bm, logsig,
                                                W1F, W2F, A3F, c_all);
    rde_main<<<dim3(32), dim3(512), 0, stream>>>(
        ts, x0, ivls, bvf1, bvf2, Win, bin, Wout, bout,
        W1F, W2F, A3F, c_all, out);
}

// Round 5
// 239.157 us; speedup vs baseline: 1.5814x; 1.0628x over previous
//
#include <hip/hip_runtime.h>

#define YW 136   // f32 elems per Ys row (128 + 8 pad)

typedef _Float16 f16x8 __attribute__((ext_vector_type(8)));
typedef _Float16 f16x4 __attribute__((ext_vector_type(4)));
typedef __attribute__((ext_vector_type(4))) float f32x4;

// 5-op tanh: 1 - 2/(e^{2x}+1). Safe at +/-inf. |err| ~1e-7.
__device__ __forceinline__ float fast_tanh(float x) {
    float e = __expf(2.0f * x);
    return 1.0f - 2.0f / (e + 1.0f);
}
// Workgroup barrier ordering LDS only — does NOT drain vmcnt, so global
// loads issued before it stay in flight across it.
__device__ __forceinline__ void bar_lds() {
    asm volatile("s_waitcnt lgkmcnt(0)\n\ts_barrier" ::: "memory");
}

// Activation planes are stored in MFMA FRAGMENT ORDER: plane[kc][lane][j],
// addr = kc*512 + lane*8 + j halfs, element (row m=lane&15, col kc*32+(lane>>4)*8+j).
// Stage reads are then lane-contiguous 16B (the proven conflict-free pattern,
// round-2: bank conflicts 2.05M -> 0.41M). fidx maps (row m, col c) -> half idx
// for commit writes.
__device__ __forceinline__ int fidx(int m, int c) {
    return ((c >> 5) << 9) | (((c >> 3) & 3) << 7) | (m << 3) | (c & 7);
}

// ---------------- fused precompute: weights -> MFMA fragment layout, hi/lo fp16 ----
// F layout: [plane][nt][kc][lane(64)][j(8)]; value = W[n*K+k], n=nt*16+(l&15),
// k=kc*32+(l>>4)*8+j. Same lane formula serves as A- or B-operand fragment.
__global__ __launch_bounds__(256) void pk_all(
    const float* __restrict__ Wvf1, const float* __restrict__ Wvf2,
    const float* __restrict__ Wm,   const float* __restrict__ bm,
    const float* __restrict__ logsig,
    _Float16* __restrict__ W1F, _Float16* __restrict__ W2F,
    _Float16* __restrict__ A3F, float* __restrict__ c_all)
{
    __shared__ float ls[32][62];
    const int b = blockIdx.x, t = threadIdx.x;
    if (b < 128) {                      // W1: N=256 x K=128 (16 nt, 4 kc)
        int u = b * 256 + t;
        int j = u & 7, l = (u >> 3) & 63;
        int kc = (u >> 9) & 3, nt = (u >> 9) >> 2;
        int n = nt * 16 + (l & 15), k = kc * 32 + (l >> 4) * 8 + j;
        float w = Wvf1[n * 128 + k];
        _Float16 hi = (_Float16)w;
        W1F[u] = hi;
        W1F[32768 + u] = (_Float16)(w - (float)hi);
    } else if (b < 384) {               // W2: 256x256 (16 nt, 8 kc)
        int u = (b - 128) * 256 + t;
        int j = u & 7, l = (u >> 3) & 63;
        int kc = (u >> 9) & 7, nt = (u >> 9) >> 3;
        int n = nt * 16 + (l & 15), k = kc * 32 + (l >> 4) * 8 + j;
        float w = Wvf2[n * 256 + k];
        _Float16 hi = (_Float16)w;
        W2F[u] = hi;
        W2F[65536 + u] = (_Float16)(w - (float)hi);
    } else if (b < 896) {               // A_r, r-chunks of 8 (4 chunks x 128 blocks)
        for (int e2 = t; e2 < 32 * 62; e2 += 256)
            ls[e2 / 62][e2 % 62] = logsig[(e2 / 62) * 63 + 1 + (e2 % 62)];
        __syncthreads();
        int idx = b - 384;
        int chunk = idx >> 7;
        int u = (idx & 127) * 256 + t;
        int j = u & 7, l = (u >> 3) & 63, kc = (u >> 9) & 7, nt = (u >> 12) & 7;
        int h = nt * 16 + (l & 15);
        int v = kc * 32 + (l >> 4) * 8 + j;
        int r0 = chunk * 8;
        float acc[8];
#pragma unroll
        for (int r = 0; r < 8; r++) acc[r] = 0.f;
        // full unroll: 62 independent Wm loads pipeline instead of serializing
#pragma unroll
        for (int ll = 0; ll < 62; ll++) {
            float wv2 = Wm[(h * 62 + ll) * 256 + v];
#pragma unroll
            for (int r = 0; r < 8; r++) acc[r] += wv2 * ls[r0 + r][ll];
        }
#pragma unroll
        for (int r = 0; r < 8; r++) {
            _Float16 hi = (_Float16)acc[r];
            A3F[(r0 + r) * 65536 + u] = hi;
            A3F[(r0 + r) * 65536 + 32768 + u] = (_Float16)(acc[r] - (float)hi);
        }
    } else {                            // c_r[h] = bm[h,:] . seg_r
        int u = (b - 896) * 256 + t;
        int r = u >> 7, h = u & 127;
        float acc = 0.f;
#pragma unroll
        for (int ll = 0; ll < 62; ll++) acc += bm[h * 62 + ll] * logsig[r * 63 + 1 + ll];
        c_all[u] = acc;
    }
}

// ---------------- main fused kernel: 32 blocks x 16 rows, 8 waves, 20-step Heun ---
// v6 (from proven round-3 skeleton, no inline-asm MFMA, no lambda):
//  * y state keeps full fp16 hi/lo 3-chain in S1 (it INTEGRATES -> protect it).
//  * h1/h2 are within-eval transients -> committed HI-ONLY; S2/S3 become
//    2-chain (weights stay hi/lo-exact). Halves S2/S3 act LDS reads + commits.
//  * W1 hi in LDS (64 KB); W1 lo streamed from global, prefetched at S3-end
//    for the next eval (in flight across the barrier, like w2a).
//  * 3-barrier flow: S1 Y->H1 | S2 H1->H2 | S3 H2->Y. No in-place commits.
// LDS reads/wave/eval: 56 -> 32 b128. MFMA 96 -> 72.
__global__ __launch_bounds__(512, 2) void rde_main(
    const float* __restrict__ ts, const float* __restrict__ x0,
    const float* __restrict__ intervals,
    const float* __restrict__ b1g, const float* __restrict__ b2g,
    const float* __restrict__ Win, const float* __restrict__ bin,
    const float* __restrict__ Wout, const float* __restrict__ bout,
    const _Float16* __restrict__ W1F, const _Float16* __restrict__ W2F,
    const _Float16* __restrict__ A3F, const float* __restrict__ c_all,
    float* __restrict__ out)
{
    __shared__ __align__(16) _Float16 W1s[32768];   // 64 KB: W1 HI frags
    __shared__ __align__(16) _Float16 H1h[4096];    // h1 hi plane (16x256)
    __shared__ __align__(16) _Float16 H2h[4096];    // h2 hi plane (16x256)
    __shared__ __align__(16) _Float16 Yh[2048];     // y hi plane (16x128)
    __shared__ __align__(16) _Float16 Yl[2048];     // y lo plane
    __shared__ float ivl[33];
    __shared__ int   r_arr[40];
    __shared__ float s_arr[40];

    const int t    = threadIdx.x;
    const int lane = t & 63;
    const int wv   = t >> 6;        // wave 0..7
    const int m16  = lane & 15;     // batch row within tile
    const int q    = lane >> 4;
    const int row0 = blockIdx.x * 16;

    if (t < 33) ivl[t] = intervals[t];
    // W1 hi -> LDS once: 32768 halfs = 4096 uint4
    for (int e2 = t; e2 < 4096; e2 += 512)
        ((uint4*)W1s)[e2] = ((const uint4*)W1F)[e2];
    __syncthreads();

    const float ts0 = ts[0];
    const float dt  = __fdiv_rn(ts[32] - ts0, 20.0f);   // bit-exact vs reference

    if (t < 40) {   // searchsorted idx + 1/delta for all 40 VF evals
        int i = t >> 1;
        float tv = ts0 + (float)i * dt;
        if (t & 1) tv += dt;
        int p = 0;
        for (int j2 = 0; j2 < 32; j2++) p += (ivl[1 + j2] < tv) ? 1 : 0;
        int idx = p + 1;
        idx = idx < 1 ? 1 : idx;
        idx = idx > 32 ? 32 : idx;
        r_arr[t] = idx - 1;
        s_arr[t] = __fdiv_rn(1.0f, ivl[idx] - ivl[idx - 1]);
    }

    // biases along D rows (q*4+r) for this wave's stage1/2 n-tiles wv*2, wv*2+1
    f32x4 b1f[2], b2f[2];
#pragma unroll
    for (int tt = 0; tt < 2; tt++) {
        b1f[tt] = *(const f32x4*)(b1g + (wv * 2 + tt) * 16 + q * 4);
        b2f[tt] = *(const f32x4*)(b2g + (wv * 2 + tt) * 16 + q * 4);
    }

    // y0 = x0 @ Win.T + bin -> Y regs + Y planes (stage3 D layout: rows q*4+r, col wv*16+m16)
    float Y[4], K1[4];
    {
        const float* xr = x0 + (row0 + m16) * 5;
        float xv[5];
#pragma unroll
        for (int d = 0; d < 5; d++) xv[d] = xr[d];
        int c0 = wv * 16 + q * 4;
        f16x4 hv, lv;
#pragma unroll
        for (int r = 0; r < 4; r++) {
            float acc = bin[c0 + r];
#pragma unroll
            for (int d = 0; d < 5; d++) acc += xv[d] * Win[(c0 + r) * 5 + d];
            Y[r] = acc;
            K1[r] = 0.f;
            _Float16 hi = (_Float16)acc;
            hv[r] = hi;
            lv[r] = (_Float16)(acc - (float)hi);
        }
        *(f16x4*)(Yh + fidx(m16, c0)) = hv;    // 512 thr x 4 = full 16x128
        *(f16x4*)(Yl + fidx(m16, c0)) = lv;
    }

    // prologue: W1-lo fragments for eval 0 (loop-carried, refreshed each S3-end)
    f16x8 w1lo[2][4];
#pragma unroll
    for (int tt = 0; tt < 2; tt++)
#pragma unroll
        for (int kc = 0; kc < 4; kc++)
            w1lo[tt][kc] = *(const f16x8*)(W1F + 32768 + ((wv * 8 + tt * 4 + kc) * 64 + lane) * 8);
    __syncthreads();

#pragma unroll 1
    for (int e = 0; e < 40; e++) {
        const int half = e & 1;
        const int ri   = r_arr[e];
        const float s  = s_arr[e];
        const _Float16* ABase = A3F + ri * 65536;

        // ---- stage1: h1 = relu(W1 . y), K=128; 3-chain (y integrates) ----
        // issue W2 window A (kc 0..3) first — in flight across all of stage1
        f16x8 w2a[2][4][2];
#pragma unroll
        for (int tt = 0; tt < 2; tt++)
#pragma unroll
            for (int kc = 0; kc < 4; kc++) {
                const _Float16* bp = W2F + ((wv * 16 + tt * 8 + kc) * 64 + lane) * 8;
                w2a[tt][kc][0] = *(const f16x8*)bp;
                w2a[tt][kc][1] = *(const f16x8*)(bp + 65536);
            }
        f32x4 aA[2], aB[2], aC[2];
#pragma unroll
        for (int tt = 0; tt < 2; tt++) {
            aA[tt] = b1f[tt];
            aB[tt] = (f32x4){0.f, 0.f, 0.f, 0.f};
            aC[tt] = (f32x4){0.f, 0.f, 0.f, 0.f};
        }
#pragma unroll
        for (int kc = 0; kc < 4; kc++) {
            f16x8 ah = *(const f16x8*)(Yh + kc * 512 + lane * 8);
            f16x8 al = *(const f16x8*)(Yl + kc * 512 + lane * 8);
#pragma unroll
            for (int tt = 0; tt < 2; tt++) {
                f16x8 bh = *(const f16x8*)(W1s + ((wv * 8 + tt * 4 + kc) * 64 + lane) * 8);
                aA[tt] = __builtin_amdgcn_mfma_f32_16x16x32_f16(bh, ah, aA[tt], 0, 0, 0);
                aB[tt] = __builtin_amdgcn_mfma_f32_16x16x32_f16(w1lo[tt][kc], ah, aB[tt], 0, 0, 0);
                aC[tt] = __builtin_amdgcn_mfma_f32_16x16x32_f16(bh, al, aC[tt], 0, 0, 0);
            }
        }
#pragma unroll
        for (int tt = 0; tt < 2; tt++) {        // commit h1 (hi only) -> H1
            int n0 = (wv * 2 + tt) * 16 + q * 4;
            f16x4 hv;
#pragma unroll
            for (int r = 0; r < 4; r++)         // D: col=lane&15 (m), row=q*4+r (n)
                hv[r] = (_Float16)fmaxf(aA[tt][r] + aB[tt][r] + aC[tt][r], 0.f);
            *(f16x4*)(H1h + fidx(m16, n0)) = hv;
        }
        bar_lds();                              // (1) h1 visible; Y reads done

        // ---- stage2: h2 = tanh(W2 . h1), K=256; 2-chain; w2a preloaded ----
        f16x8 w2b[2][4][2];
#pragma unroll
        for (int tt = 0; tt < 2; tt++)
#pragma unroll
            for (int kc = 0; kc < 4; kc++) {
                const _Float16* bp = W2F + ((wv * 16 + tt * 8 + 4 + kc) * 64 + lane) * 8;
                w2b[tt][kc][0] = *(const f16x8*)bp;
                w2b[tt][kc][1] = *(const f16x8*)(bp + 65536);
            }
#pragma unroll
        for (int tt = 0; tt < 2; tt++) {
            aA[tt] = b2f[tt];
            aB[tt] = (f32x4){0.f, 0.f, 0.f, 0.f};
        }
#pragma unroll
        for (int kc = 0; kc < 4; kc++) {        // first half with w2a
            f16x8 ah = *(const f16x8*)(H1h + kc * 512 + lane * 8);
#pragma unroll
            for (int tt = 0; tt < 2; tt++) {
                aA[tt] = __builtin_amdgcn_mfma_f32_16x16x32_f16(w2a[tt][kc][0], ah, aA[tt], 0, 0, 0);
                aB[tt] = __builtin_amdgcn_mfma_f32_16x16x32_f16(w2a[tt][kc][1], ah, aB[tt], 0, 0, 0);
            }
        }
        // issue A_r window A (kc 0..3; stage3 n-tile = wv) + c vector
        f16x8 a3a[4][2];
#pragma unroll
        for (int kc = 0; kc < 4; kc++) {
            const _Float16* bp = ABase + ((wv * 8 + kc) * 64 + lane) * 8;
            a3a[kc][0] = *(const f16x8*)bp;
            a3a[kc][1] = *(const f16x8*)(bp + 32768);
        }
        f32x4 cf = *(const f32x4*)(c_all + ri * 128 + wv * 16 + q * 4);
#pragma unroll
        for (int kc = 0; kc < 4; kc++) {        // second half with w2b
            f16x8 ah = *(const f16x8*)(H1h + (4 + kc) * 512 + lane * 8);
#pragma unroll
            for (int tt = 0; tt < 2; tt++) {
                aA[tt] = __builtin_amdgcn_mfma_f32_16x16x32_f16(w2b[tt][kc][0], ah, aA[tt], 0, 0, 0);
                aB[tt] = __builtin_amdgcn_mfma_f32_16x16x32_f16(w2b[tt][kc][1], ah, aB[tt], 0, 0, 0);
            }
        }
        // issue A_r window B (kc 4..7)
        f16x8 a3b[4][2];
#pragma unroll
        for (int kc = 0; kc < 4; kc++) {
            const _Float16* bp = ABase + ((wv * 8 + 4 + kc) * 64 + lane) * 8;
            a3b[kc][0] = *(const f16x8*)bp;
            a3b[kc][1] = *(const f16x8*)(bp + 32768);
        }
#pragma unroll
        for (int tt = 0; tt < 2; tt++) {        // commit h2 (tanh, hi only) -> H2
            int n0 = (wv * 2 + tt) * 16 + q * 4;
            f16x4 hv;
#pragma unroll
            for (int r = 0; r < 4; r++)
                hv[r] = (_Float16)fast_tanh(aA[tt][r] + aB[tt][r]);
            *(f16x4*)(H2h + fidx(m16, n0)) = hv;
        }
        bar_lds();                              // (2) h2 visible; H1 reads done

        // ---- stage3: k = (A_r . h2 + c) * s; 2-chain ----
        f32x4 kA = cf;
        f32x4 kB = (f32x4){0.f, 0.f, 0.f, 0.f};
#pragma unroll
        for (int kc = 0; kc < 4; kc++) {        // kc 0..3 with a3a
            f16x8 ah = *(const f16x8*)(H2h + kc * 512 + lane * 8);
            kA = __builtin_amdgcn_mfma_f32_16x16x32_f16(a3a[kc][0], ah, kA, 0, 0, 0);
            kB = __builtin_amdgcn_mfma_f32_16x16x32_f16(a3a[kc][1], ah, kB, 0, 0, 0);
        }
#pragma unroll
        for (int kc = 0; kc < 4; kc++) {        // kc 4..7 with a3b
            f16x8 ah = *(const f16x8*)(H2h + (4 + kc) * 512 + lane * 8);
            kA = __builtin_amdgcn_mfma_f32_16x16x32_f16(a3b[kc][0], ah, kA, 0, 0, 0);
            kB = __builtin_amdgcn_mfma_f32_16x16x32_f16(a3b[kc][1], ah, kB, 0, 0, 0);
        }
        // prefetch next eval's W1-lo frags (in flight across commit + barrier)
#pragma unroll
        for (int tt = 0; tt < 2; tt++)
#pragma unroll
            for (int kc = 0; kc < 4; kc++)
                w1lo[tt][kc] = *(const f16x8*)(W1F + 32768 + ((wv * 8 + tt * 4 + kc) * 64 + lane) * 8);
        {                                       // Heun commit + y' -> Y planes
            int c0 = wv * 16 + q * 4;
            f16x4 hv, lv;
#pragma unroll
            for (int r = 0; r < 4; r++) {
                float kv = (kA[r] + kB[r]) * s;
                float yn;
                if (half == 0) {                 // k1: stash, form y+dt*k1
                    K1[r] = kv;
                    yn = Y[r] + dt * kv;
                } else {                         // k2: y += 0.5*dt*(k1+k2)
                    yn = Y[r] + 0.5f * dt * (K1[r] + kv);
                    Y[r] = yn;
                }
                _Float16 hi = (_Float16)yn;
                hv[r] = hi;
                lv[r] = (_Float16)(yn - (float)hi);
            }
            *(f16x4*)(Yh + fidx(m16, c0)) = hv;
            *(f16x4*)(Yl + fidx(m16, c0)) = lv;
        }
        bar_lds();                              // (3) y' visible; H2 free
    }

    // epilogue: overlay Ys (16xYW f32) + lg onto dead W1s (64 KB)
    float* Ys  = (float*)&W1s[0];               // 8704 B
    float* lgp = (float*)&W1s[0] + 16 * YW;     // 640 B
#pragma unroll
    for (int r = 0; r < 4; r++)
        Ys[m16 * YW + wv * 16 + q * 4 + r] = Y[r];
    __syncthreads();
    if (t < 160) {                  // logits
        int m = t / 10, c = t % 10;
        float acc = bout[c];
        for (int k = 0; k < 128; k++) acc += Ys[m * YW + k] * Wout[c * 128 + k];
        lgp[m * 10 + c] = acc;
    }
    __syncthreads();
    if (t < 16) {                   // softmax
        float mx = -1e30f;
#pragma unroll
        for (int c = 0; c < 10; c++) mx = fmaxf(mx, lgp[t * 10 + c]);
        float ex[10], sum = 0.f;
#pragma unroll
        for (int c = 0; c < 10; c++) { ex[c] = expf(lgp[t * 10 + c] - mx); sum += ex[c]; }
        float inv = __fdiv_rn(1.0f, sum);
#pragma unroll
        for (int c = 0; c < 10; c++) out[(row0 + t) * 10 + c] = ex[c] * inv;
    }
}

extern "C" void kernel_launch(void* const* d_in, const int* in_sizes, int n_in,
                              void* d_out, int out_size, void* d_ws, size_t ws_size,
                              hipStream_t stream) {
    const float* ts     = (const float*)d_in[0];
    const float* logsig = (const float*)d_in[1];
    const float* x0     = (const float*)d_in[2];
    const float* ivls   = (const float*)d_in[3];
    const float* Wvf1   = (const float*)d_in[4];
    const float* bvf1   = (const float*)d_in[5];
    const float* Wvf2   = (const float*)d_in[6];
    const float* bvf2   = (const float*)d_in[7];
    const float* Wm     = (const float*)d_in[8];
    const float* bm     = (const float*)d_in[9];
    const float* Win    = (const float*)d_in[10];
    const float* bin    = (const float*)d_in[11];
    const float* Wout   = (const float*)d_in[12];
    const float* bout   = (const float*)d_in[13];

    _Float16* W1F = (_Float16*)d_ws;            // 65536 halfs (128KB, hi+lo)
    _Float16* W2F = W1F + 65536;                // 131072 halfs (256KB, hi+lo)
    _Float16* A3F = W2F + 131072;               // 32*65536 halfs (4MB, hi+lo per r)
    float* c_all = (float*)(A3F + 32 * 65536);  // 4096 f32 (16KB)
    float* out = (float*)d_out;

    pk_all<<<dim3(912), dim3(256), 0, stream>>>(Wvf1, Wvf2, Wm, bm, logsig,
                                                W1F, W2F, A3F, c_all);
    rde_main<<<dim3(32), dim3(512), 0, stream>>>(
        ts, x0, ivls, bvf1, bvf2, Win, bin, Wout, bout,
        W1F, W2F, A3F, c_all, out);
}